// Round 1
// baseline (925.661 us; speedup 1.0000x reference)
//
#include <hip/hip_runtime.h>
#include <math.h>

// Problem constants
#define BT     4096      // B*T tokens per pass
#define M_TOT  8192      // 2 passes stacked
#define KDIM   768
#define VDIM   50257
#define NBLK   393       // ceil(VDIM/128)
#define NB256  197       // ceil(VDIM/256)
#define KCH    24        // 768 / 32 K-chunks
#define KT     12        // 768 / 64 K-tiles
#define REWARD_SCALE 0.5
#define DIV_WEIGHT   0.1
#define EPS_COS      1e-8f
#define LOG2E        1.44269504088896340736f

typedef _Float16 half8 __attribute__((ext_vector_type(8)));
typedef float    f32x4 __attribute__((ext_vector_type(4)));

#define A_FRAGS (64*KCH*8*64)      // 786432  fragments of 16B (f16)
#define W_FRAGS (NBLK*KCH*8*64)    // 4829184 fragments of 16B

// ---------------------------------------------------------------------------
// async global->LDS, 16B per lane (wave-uniform base + lane*16 semantics)
// ---------------------------------------------------------------------------
__device__ __forceinline__ void g2l16(const short* g, short* l) {
    __builtin_amdgcn_global_load_lds(
        (const __attribute__((address_space(1))) unsigned int*)(const void*)g,
        (__attribute__((address_space(3))) unsigned int*)(void*)l,
        16, 0, 0);
}

// ---------------------------------------------------------------------------
// Converters: fp32 -> f16, pre-swizzled into MFMA fragment order (LDS
// transpose for coalesced reads).  W additionally scaled by log2(e) so the
// GEMM's logits come out in base-2 (epilogue = single v_exp_f32).
// Frag layout: ((blk*KCH + k0)*8 + tile)*64 + lane ; lane gives
//   [row = blk*128 + tile*16 + (lane&15)][k = k0*32 + (lane>>4)*8 + j]
// ---------------------------------------------------------------------------
__global__ __launch_bounds__(256)
void convert_A_kernel(const float* __restrict__ p2, const float* __restrict__ p3,
                      short* __restrict__ Ahi)
{
    __shared__ float Ls[128][36];
    const int mb = blockIdx.x;             // 0..63
    const int k0 = blockIdx.y;             // 0..23
    const int tid = threadIdx.x;

#pragma unroll
    for (int p = 0; p < 4; ++p) {
        int i = p * 1024 + tid * 4;
        int r = i >> 5;
        int c = i & 31;
        int m = mb * 128 + r;
        const float* src = (m < BT) ? (p2 + (size_t)m * KDIM)
                                    : (p3 + (size_t)(m - BT) * KDIM);
        float4 v = *(const float4*)(src + k0 * 32 + c);
        *(float4*)&Ls[r][c] = v;
    }
    __syncthreads();

    size_t base = ((size_t)(mb * KCH + k0) * 8) * 64;
#pragma unroll
    for (int h = 0; h < 2; ++h) {
        int f    = tid + h * 256;
        int lane = f & 63;
        int tile = f >> 6;
        int row  = tile * 16 + (lane & 15);
        int kq   = (lane >> 4) * 8;
        half8 out;
#pragma unroll
        for (int j = 0; j < 8; ++j) out[j] = (_Float16)Ls[row][kq + j];
        *(half8*)(Ahi + (base + f) * 8) = out;
    }
}

__global__ __launch_bounds__(256)
void convert_W_kernel(const float* __restrict__ W, short* __restrict__ Whi)
{
    __shared__ float Ls[128][36];
    const int nb = blockIdx.x;             // 0..392
    const int k0 = blockIdx.y;             // 0..23
    const int tid = threadIdx.x;

#pragma unroll
    for (int p = 0; p < 4; ++p) {
        int i = p * 1024 + tid * 4;
        int r = i >> 5;
        int c = i & 31;
        int v = nb * 128 + r;
        float4 val = make_float4(0.f, 0.f, 0.f, 0.f);
        if (v < VDIM) val = *(const float4*)(W + (size_t)v * KDIM + k0 * 32 + c);
        *(float4*)&Ls[r][c] = val;
    }
    __syncthreads();

    size_t base = ((size_t)(nb * KCH + k0) * 8) * 64;
#pragma unroll
    for (int h = 0; h < 2; ++h) {
        int f    = tid + h * 256;
        int lane = f & 63;
        int tile = f >> 6;
        int row  = tile * 16 + (lane & 15);
        int kq   = (lane >> 4) * 8;
        half8 out;
#pragma unroll
        for (int j = 0; j < 8; ++j) out[j] = (_Float16)(Ls[row][kq + j] * LOG2E);
        *(half8*)(Whi + (base + f) * 8) = out;
    }
}

// ---------------------------------------------------------------------------
// Main GEMM: 256x256 block tile, 512 threads (8 waves 2Mx4N), wave tile
// 128x64.  Both A and B staged via global_load_lds (128 KB LDS, 2-deep
// double buffer).  4-phase/K-tile schedule with COUNTED vmcnt (never 0 in
// steady state), raw s_barrier (asm, memory-clobbered), sched_barrier(0)
// fences, s_setprio(1) around MFMA clusters.  Fragment layout is linear in
// LDS -> 0 bank conflicts, no T2 swizzle needed.
//
// vmcnt bookkeeping (8 stage ops/wave/K-tile; h0 group of 4, then h1 group
// of 4, issued at P0 of the PREVIOUS tile):
//   tile entry:  vmcnt(4)  -> H(kt,h0) resident  (allows H(kt,h1) in flight)
//   end of P1:   vmcnt(8)  -> H(kt,h1) resident  (allows H(kt+1)'s 8)
//   end of P3:   vmcnt(4)  -> H(kt+1,h0) resident (== next tile's entry)
// ---------------------------------------------------------------------------
#define BARRIER()  asm volatile("s_barrier" ::: "memory")
#define WAITV(n_)  asm volatile("s_waitcnt vmcnt(" #n_ ")" ::: "memory")
#define SB0()      __builtin_amdgcn_sched_barrier(0)

__global__ __launch_bounds__(512, 2)
void gemm_f16_kernel(const short* __restrict__ Ahi, const short* __restrict__ Whi,
                     double* __restrict__ g_sumexp)
{
    __shared__ __align__(16) short As[2][32][64][8];   // 64 KB
    __shared__ __align__(16) short Bs[2][32][64][8];   // 64 KB

    const int tid  = threadIdx.x;
    const int lane = tid & 63;
    const int w    = tid >> 6;        // 0..7
    const int wm   = w >> 2;          // 0..1  (M half: 128 rows)
    const int wn   = w & 3;           // 0..3  (N quarter: 64 cols)
    const int mb   = blockIdx.x;      // 0..31  (256-row M blocks)
    const int nb   = blockIdx.y;      // 0..196 (256-col N blocks)

    // ---- staging roles: waves 0-3 stage A, waves 4-7 stage B (4 rows each)
    const int  f0       = (w & 3) * 4;      // first frag-row (of 16) staged
    const int  sh       = f0 >> 3;          // mbh / nbh (sub-block of 128)
    const int  tileBase = f0 & 7;
    const bool isB      = (w >= 4);
    const int  nb128    = min(2 * nb + sh, NBLK - 1);   // clamp last N tile
    const short* gbase  = isB
        ? Whi + (size_t)nb128 * KCH * 4096 + lane * 8
        : Ahi + (size_t)(2 * mb + sh) * KCH * 4096 + lane * 8;
    short* stageL = (isB ? &Bs[0][0][0][0] : &As[0][0][0][0])
                    + lane * 8 + f0 * 512;

    // stage one K-half (k0 chunk kc_) into buffer bufn_: 4 x g2l16
#define STAGEH(kc_, bufn_)                                                    \
    {                                                                         \
        short* l0 = stageL + ((bufn_) * 32 + ((kc_) & 1) * 16) * 512;         \
        const short* g0 = gbase + (size_t)((kc_) * 8 + tileBase) * 512;       \
        _Pragma("unroll")                                                     \
        for (int j = 0; j < 4; ++j) g2l16(g0 + j * 512, l0 + j * 512);        \
    }

    // ---- ds_read bases (fragment rows are linear 1KB -> conflict-free)
    const short* aRd = &As[0][wm * 8][lane][0];
    const short* bRd = &Bs[0][(wn >> 1) * 8 + (wn & 1) * 4][lane][0];
#define RDA(CUR_, kh_, mh_, i_) \
    (*(const half8*)(aRd + ((CUR_) * 32 + (kh_) * 16 + (mh_) * 4 + (i_)) * 512))
#define RDB(CUR_, kh_, i_) \
    (*(const half8*)(bRd + ((CUR_) * 32 + (kh_) * 16 + (i_)) * 512))

    f32x4 acc[8][4];
#pragma unroll
    for (int i = 0; i < 8; ++i)
#pragma unroll
        for (int j = 0; j < 4; ++j) acc[i][j] = (f32x4)0.0f;

#define MFMA16(mh_)                                                           \
    __builtin_amdgcn_s_setprio(1);                                            \
    _Pragma("unroll")                                                         \
    for (int mt = 0; mt < 4; ++mt)                                            \
        _Pragma("unroll")                                                     \
        for (int nt = 0; nt < 4; ++nt)                                        \
            acc[(mh_) * 4 + mt][nt] = __builtin_amdgcn_mfma_f32_16x16x32_f16( \
                a[mt], b[nt], acc[(mh_) * 4 + mt][nt], 0, 0, 0);              \
    __builtin_amdgcn_s_setprio(0);

    // one K-tile (BK=64): 4 phases, 16 MFMA each; CUR_/STG_/LAST_ literal
#define KTILE(kt_, CUR_, STG_, LAST_)                                         \
    {                                                                         \
        half8 a[4], b[4];                                                     \
        /* P0: issue next tile's stages (h0 group, then h1 group) */          \
        if (STG_) {                                                           \
            STAGEH(2 * ((kt_) + 1), (CUR_) ^ 1);                              \
            SB0();                                                            \
            STAGEH(2 * ((kt_) + 1) + 1, (CUR_) ^ 1);                          \
        }                                                                     \
        _Pragma("unroll")                                                     \
        for (int i = 0; i < 4; ++i) {                                         \
            a[i] = RDA(CUR_, 0, 0, i);                                        \
            b[i] = RDB(CUR_, 0, i);                                           \
        }                                                                     \
        BARRIER(); SB0();                                                     \
        MFMA16(0);                                                            \
        SB0(); BARRIER();                                                     \
        /* P1 */                                                              \
        _Pragma("unroll")                                                     \
        for (int i = 0; i < 4; ++i) a[i] = RDA(CUR_, 0, 1, i);                \
        BARRIER(); SB0();                                                     \
        MFMA16(1);                                                            \
        SB0();                                                                \
        if (LAST_) { WAITV(0); } else { WAITV(8); }                           \
        BARRIER();                                                            \
        /* P2 */                                                              \
        _Pragma("unroll")                                                     \
        for (int i = 0; i < 4; ++i) {                                         \
            a[i] = RDA(CUR_, 1, 0, i);                                        \
            b[i] = RDB(CUR_, 1, i);                                           \
        }                                                                     \
        BARRIER(); SB0();                                                     \
        MFMA16(0);                                                            \
        SB0(); BARRIER();                                                     \
        /* P3 */                                                              \
        _Pragma("unroll")                                                     \
        for (int i = 0; i < 4; ++i) a[i] = RDA(CUR_, 1, 1, i);                \
        BARRIER(); SB0();                                                     \
        MFMA16(1);                                                            \
        SB0();                                                                \
        if (!(LAST_)) { WAITV(4); }                                           \
        BARRIER();                                                            \
    }

    // ---- prologue: stage K-tile 0 into buf 0, wait for its h0
    STAGEH(0, 0);
    SB0();
    STAGEH(1, 0);
    WAITV(4);
    BARRIER();

#pragma unroll 1
    for (int kt = 0; kt < 10; kt += 2) {
        KTILE(kt,     0, 1, 0)
        KTILE(kt + 1, 1, 1, 0)
    }
    KTILE(10, 0, 1, 0)
    KTILE(11, 1, 0, 1)

#undef KTILE
#undef MFMA16
#undef RDA
#undef RDB
#undef STAGEH

    // --- epilogue: exp2 (logits pre-scaled by log2e), per-row reduce ---
    __syncthreads();
    float* rowsum = (float*)&As[0][0][0][0];    // LDS reuse (staging done)
    if (tid < 256) rowsum[tid] = 0.0f;
    __syncthreads();

    const int colBase = nb * 256 + wn * 64;
    const int quad = lane >> 4;
    const int cidx = lane & 15;
#pragma unroll
    for (int mt = 0; mt < 8; ++mt) {
#pragma unroll
        for (int r = 0; r < 4; ++r) {
            float s = 0.0f;
#pragma unroll
            for (int nt = 0; nt < 4; ++nt) {
                int col = colBase + nt * 16 + cidx;
                if (col < VDIM) s += __builtin_amdgcn_exp2f(acc[mt][nt][r]);
            }
            s += __shfl_xor(s, 1);
            s += __shfl_xor(s, 2);
            s += __shfl_xor(s, 4);
            s += __shfl_xor(s, 8);
            if (cidx == 0) {
                int row = wm * 128 + mt * 16 + quad * 4 + r;
                atomicAdd(&rowsum[row], s);
            }
        }
    }
    __syncthreads();
    if (tid < 256) {
        atomicAdd(&g_sumexp[(size_t)mb * 256 + tid], (double)rowsum[tid]);
    }
}

// ---------------------------------------------------------------------------
// Fallback fp32 GEMM (round-2 kernel) if workspace is too small.
// ---------------------------------------------------------------------------
#define BM 128
#define BN 128
#define BK 16
#define LDPAD 4
__global__ __launch_bounds__(256)
void logits_expsum_kernel(const float* __restrict__ p2,
                          const float* __restrict__ p3,
                          const float* __restrict__ W,
                          double* __restrict__ g_sumexp)
{
    __shared__ float As[BK][BM + LDPAD];
    __shared__ float Bsh[BK][BN + LDPAD];
    __shared__ float rowsum[BM];

    const int tid     = threadIdx.x;
    const int rowBase = blockIdx.y * BM;
    const int colBase = blockIdx.x * BN;

    if (tid < BM) rowsum[tid] = 0.0f;

    float acc[8][8];
#pragma unroll
    for (int i = 0; i < 8; ++i)
#pragma unroll
        for (int j = 0; j < 8; ++j) acc[i][j] = 0.0f;

    const int ty = tid >> 4;
    const int tx = tid & 15;
    const int r0 = ty * 8;
    const int c0 = tx * 4;

    for (int k0 = 0; k0 < KDIM; k0 += BK) {
        __syncthreads();
#pragma unroll
        for (int l = 0; l < 2; ++l) {
            int id  = tid + l * 256;
            int row = id >> 2;
            int kq  = id & 3;
            int m   = rowBase + row;
            const float* src = (m < BT) ? (p2 + (size_t)m * KDIM)
                                        : (p3 + (size_t)(m - BT) * KDIM);
            float4 v = *(const float4*)(src + k0 + kq * 4);
            As[kq * 4 + 0][row] = v.x;
            As[kq * 4 + 1][row] = v.y;
            As[kq * 4 + 2][row] = v.z;
            As[kq * 4 + 3][row] = v.w;
        }
#pragma unroll
        for (int l = 0; l < 2; ++l) {
            int id  = tid + l * 256;
            int row = id >> 2;
            int kq  = id & 3;
            int c   = colBase + row;
            int cs  = (c < VDIM) ? c : (VDIM - 1);
            float4 v = *(const float4*)(W + (size_t)cs * KDIM + k0 + kq * 4);
            Bsh[kq * 4 + 0][row] = v.x;
            Bsh[kq * 4 + 1][row] = v.y;
            Bsh[kq * 4 + 2][row] = v.z;
            Bsh[kq * 4 + 3][row] = v.w;
        }
        __syncthreads();
#pragma unroll
        for (int kk = 0; kk < BK; ++kk) {
            float a[8], bb[8];
            *(float4*)&a[0]  = *(const float4*)&As[kk][r0];
            *(float4*)&a[4]  = *(const float4*)&As[kk][r0 + 4];
            *(float4*)&bb[0] = *(const float4*)&Bsh[kk][c0];
            *(float4*)&bb[4] = *(const float4*)&Bsh[kk][64 + c0];
#pragma unroll
            for (int i = 0; i < 8; ++i)
#pragma unroll
                for (int j = 0; j < 8; ++j)
                    acc[i][j] = fmaf(a[i], bb[j], acc[i][j]);
        }
    }

    __syncthreads();
#pragma unroll
    for (int i = 0; i < 8; ++i) {
        float s = 0.0f;
#pragma unroll
        for (int j = 0; j < 8; ++j) {
            int c = colBase + ((j < 4) ? (c0 + j) : (64 + c0 + (j - 4)));
            if (c < VDIM) s += expf(acc[i][j]);
        }
        atomicAdd(&rowsum[r0 + i], s);
    }
    __syncthreads();
    if (tid < BM) {
        atomicAdd(&g_sumexp[rowBase + tid], (double)rowsum[tid]);
    }
}

// ---------------------------------------------------------------------------
// Kernel 2: per token — exact fp32 target logits + cosine.  NO atomics:
// writes per-token values; reduced by final_scalar_kernel.
// tokvals[t] = {nll2, nll3, cos, valid}
// ---------------------------------------------------------------------------
__global__ __launch_bounds__(256)
void finalize_tokens_kernel(const float* __restrict__ p2,
                            const float* __restrict__ p3,
                            const float* __restrict__ W,
                            const int*   __restrict__ targets,
                            const double* __restrict__ g_sumexp,
                            double* __restrict__ tokvals)
{
    const int t   = blockIdx.x;
    const int tid = threadIdx.x;
    const int tg  = targets[t];
    const bool valid = (tg >= 0);
    const float* w = W + (size_t)(valid ? tg : 0) * KDIM;
    const float* a = p2 + (size_t)t * KDIM;
    const float* b = p3 + (size_t)t * KDIM;

    float s22 = 0.f, s33 = 0.f, s23 = 0.f, s2w = 0.f, s3w = 0.f;
    for (int i = tid; i < KDIM; i += 256) {
        float x = a[i], y = b[i], ww = w[i];
        s22 = fmaf(x, x, s22);
        s33 = fmaf(y, y, s33);
        s23 = fmaf(x, y, s23);
        s2w = fmaf(x, ww, s2w);
        s3w = fmaf(y, ww, s3w);
    }
#pragma unroll
    for (int off = 32; off > 0; off >>= 1) {
        s22 += __shfl_down(s22, off);
        s33 += __shfl_down(s33, off);
        s23 += __shfl_down(s23, off);
        s2w += __shfl_down(s2w, off);
        s3w += __shfl_down(s3w, off);
    }
    __shared__ float sm[5][4];
    const int wv = tid >> 6, lane = tid & 63;
    if (lane == 0) {
        sm[0][wv] = s22; sm[1][wv] = s33; sm[2][wv] = s23;
        sm[3][wv] = s2w; sm[4][wv] = s3w;
    }
    __syncthreads();
    if (tid == 0) {
        float S22 = sm[0][0] + sm[0][1] + sm[0][2] + sm[0][3];
        float S33 = sm[1][0] + sm[1][1] + sm[1][2] + sm[1][3];
        float S23 = sm[2][0] + sm[2][1] + sm[2][2] + sm[2][3];
        float S2w = sm[3][0] + sm[3][1] + sm[3][2] + sm[3][3];
        float S3w = sm[4][0] + sm[4][1] + sm[4][2] + sm[4][3];

        float n2 = fmaxf(sqrtf(S22), EPS_COS);
        float n3 = fmaxf(sqrtf(S33), EPS_COS);

        double4 out;
        out.x = valid ? (log(g_sumexp[t])      - (double)S2w) : 0.0;
        out.y = valid ? (log(g_sumexp[BT + t]) - (double)S3w) : 0.0;
        out.z = (double)(S23 / (n2 * n3));
        out.w = valid ? 1.0 : 0.0;
        *(double4*)(tokvals + 4 * (size_t)t) = out;
    }
}

// ---------------------------------------------------------------------------
// Kernel 3: reduce tokvals -> output scalar (one 1024-thread block).
// ---------------------------------------------------------------------------
__global__ __launch_bounds__(1024)
void final_scalar_kernel(const double* __restrict__ tokvals,
                         float* __restrict__ out)
{
    const int tid = threadIdx.x;
    double s0 = 0.0, s1 = 0.0, s2 = 0.0, s3 = 0.0;
    for (int t = tid; t < BT; t += 1024) {
        double4 v = *(const double4*)(tokvals + 4 * (size_t)t);
        s0 += v.x; s1 += v.y; s2 += v.z; s3 += v.w;
    }
#pragma unroll
    for (int off = 32; off > 0; off >>= 1) {
        s0 += __shfl_down(s0, off);
        s1 += __shfl_down(s1, off);
        s2 += __shfl_down(s2, off);
        s3 += __shfl_down(s3, off);
    }
    __shared__ double sm[4][16];
    const int wv = tid >> 6, lane = tid & 63;
    if (lane == 0) { sm[0][wv] = s0; sm[1][wv] = s1; sm[2][wv] = s2; sm[3][wv] = s3; }
    __syncthreads();
    if (tid == 0) {
        double S0 = 0, S1 = 0, S2 = 0, S3 = 0;
#pragma unroll
        for (int i = 0; i < 16; ++i) { S0 += sm[0][i]; S1 += sm[1][i]; S2 += sm[2][i]; S3 += sm[3][i]; }
        double cnt = (S3 > 0.0) ? S3 : 1.0;
        double loss_p2 = S0 / cnt;
        double loss_p3 = S1 / cnt;
        double reward_loss = -REWARD_SCALE * (loss_p2 - loss_p3);
        double divergence  =  DIV_WEIGHT * (S2 / (double)BT);
        out[0] = (float)(reward_loss + divergence);
    }
}

// ---------------------------------------------------------------------------
extern "C" void kernel_launch(void* const* d_in, const int* in_sizes, int n_in,
                              void* d_out, int out_size, void* d_ws, size_t ws_size,
                              hipStream_t stream)
{
    const float* p2  = (const float*)d_in[0];   // [2,2048,768] fp32
    const float* p3  = (const float*)d_in[1];   // [2,2048,768] fp32
    const float* W   = (const float*)d_in[2];   // [50257,768] fp32
    const int*   tgt = (const int*)d_in[3];     // [2,2048]

    double* g_sumexp = (double*)d_ws;                    // 8192 doubles (64 KB)
    double* tokvals  = g_sumexp + M_TOT;                 // 16384 doubles (128 KB)
    char*   fragbase = (char*)d_ws + 196608;

    hipMemsetAsync(d_ws, 0, 65536, stream);   // g_sumexp only

    const size_t need = 196608 + (size_t)A_FRAGS * 16 + (size_t)W_FRAGS * 16;
    if (ws_size >= need) {
        short* Ahi = (short*)fragbase;
        short* Whi = Ahi + (size_t)A_FRAGS * 8;

        convert_A_kernel<<<dim3(64, KCH), dim3(256), 0, stream>>>(p2, p3, Ahi);
        convert_W_kernel<<<dim3(NBLK, KCH), dim3(256), 0, stream>>>(W, Whi);
        // grid.x = mb fast: the 32 blocks sharing an nb (same B panel, L2-
        // resident 393KB) land round-robin across XCDs, 4 per XCD-L2.
        gemm_f16_kernel<<<dim3(32, NB256), dim3(512), 0, stream>>>(Ahi, Whi, g_sumexp);
    } else {
        logits_expsum_kernel<<<dim3(NBLK, 64), dim3(256), 0, stream>>>(p2, p3, W, g_sumexp);
    }

    finalize_tokens_kernel<<<dim3(BT), dim3(256), 0, stream>>>(
        p2, p3, W, tgt, g_sumexp, tokvals);

    final_scalar_kernel<<<dim3(1), dim3(1024), 0, stream>>>(tokvals, (float*)d_out);
}